// Round 1
// baseline (355.044 us; speedup 1.0000x reference)
//
#include <hip/hip_runtime.h>

#define N_  2
#define C_  128
#define CR_ 64
#define H_  96
#define W_  96
#define L_  (H_*W_)     // 9216
#define QBLK 64
#define KVBLK 64

typedef short bf16x8 __attribute__((ext_vector_type(8)));
typedef float f32x4  __attribute__((ext_vector_type(4)));

static __device__ __forceinline__ unsigned short f2bf(float f) {
    unsigned u = __builtin_bit_cast(unsigned, f);
    unsigned rounding = 0x7FFFu + ((u >> 16) & 1u);
    return (unsigned short)((u + rounding) >> 16);
}

// ---------------------------------------------------------------------------
// Projection kernel: q = prelu(W1 x + b1), k = prelu(W2 x + b2), v = prelu(Wa x + ba)
// Outputs (bf16, in d_ws):
//   q_t [N][L][CR]  (row-major over CR -> MFMA A-frag friendly)
//   k_t [N][L][CR]  (row-major over CR -> MFMA B-frag friendly)
//   v   [N][C][L]   (L contiguous -> PV B-frag friendly)
// ---------------------------------------------------------------------------
__global__ __launch_bounds__(256) void proj_kernel(
    const float* __restrict__ x,
    const float* __restrict__ w1, const float* __restrict__ b1, const float* __restrict__ a1,
    const float* __restrict__ w2, const float* __restrict__ b2, const float* __restrict__ a2,
    const float* __restrict__ wa, const float* __restrict__ ba, const float* __restrict__ aa,
    unsigned short* __restrict__ qkv)
{
    __shared__ float xs[C_][16];
    const int blk = blockIdx.x;                // 0 .. N*L/16-1
    const int n   = blk / (L_/16);
    const int i0  = (blk % (L_/16)) * 16;
    const float* xb = x + (size_t)n * C_ * L_;

    for (int idx = threadIdx.x; idx < C_*16; idx += 256) {
        int c = idx >> 4, j = idx & 15;
        xs[c][j] = xb[(size_t)c * L_ + i0 + j];
    }
    __syncthreads();

    const int t = threadIdx.x;
    const float* wrow;
    float bias, alpha;
    int o;
    if (t < 64)       { o = t;       wrow = w1 + o*C_; bias = b1[o]; alpha = a1[0]; }
    else if (t < 128) { o = t - 64;  wrow = w2 + o*C_; bias = b2[o]; alpha = a2[0]; }
    else              { o = t - 128; wrow = wa + o*C_; bias = ba[o]; alpha = aa[0]; }

    float acc[16];
    #pragma unroll
    for (int j = 0; j < 16; j++) acc[j] = bias;

    for (int c = 0; c < C_; c++) {
        float wv = wrow[c];
        #pragma unroll
        for (int j = 0; j < 16; j++) acc[j] += wv * xs[c][j];
    }

    unsigned short vals[16];
    #pragma unroll
    for (int j = 0; j < 16; j++) {
        float y = acc[j];
        y = fmaxf(y, 0.0f) + alpha * fminf(y, 0.0f);
        vals[j] = f2bf(y);
    }

    unsigned short* q_t = qkv;
    unsigned short* k_t = qkv + (size_t)N_ * L_ * CR_;
    unsigned short* v   = qkv + (size_t)2 * N_ * L_ * CR_;

    if (t < 64) {
        unsigned short* d = q_t + (size_t)n * L_ * CR_;
        #pragma unroll
        for (int j = 0; j < 16; j++) d[(size_t)(i0 + j) * CR_ + o] = vals[j];
    } else if (t < 128) {
        unsigned short* d = k_t + (size_t)n * L_ * CR_;
        #pragma unroll
        for (int j = 0; j < 16; j++) d[(size_t)(i0 + j) * CR_ + o] = vals[j];
    } else {
        unsigned short* d = v + (size_t)n * C_ * L_ + (size_t)o * L_ + i0;
        union { unsigned short u[8]; int4 v4; } p0, p1;
        #pragma unroll
        for (int j = 0; j < 8; j++) { p0.u[j] = vals[j]; p1.u[j] = vals[8 + j]; }
        *reinterpret_cast<int4*>(d)     = p0.v4;
        *reinterpret_cast<int4*>(d + 8) = p1.v4;
    }
}

// ---------------------------------------------------------------------------
// Flash attention: out[n][c][i] = sum_j softmax_j(q_t[i].k_t[j]) * v[c][j] + x[n][c][i]
// Block: one (n, 64-row q tile). 4 waves x 16 rows. KV tiles of 64.
// ---------------------------------------------------------------------------
__global__ __launch_bounds__(256) void attn_kernel(
    const unsigned short* __restrict__ qkv,
    const float* __restrict__ x,
    float* __restrict__ out)
{
    // swizzled LDS tiles: row stride 128B, byte ^= (row&7)<<4
    __shared__ alignas(16) unsigned char k_lds[KVBLK * 128]; // [64 j][64 c] bf16
    __shared__ alignas(16) unsigned char v_lds[C_ * 128];    // [128 c][64 j] bf16
    __shared__ alignas(16) unsigned char p_lds[QBLK * 128];  // [64 i][64 j] bf16

    const unsigned short* q_t = qkv;
    const unsigned short* k_t = qkv + (size_t)N_ * L_ * CR_;
    const unsigned short* v   = qkv + (size_t)2 * N_ * L_ * CR_;

    const int blk  = blockIdx.x;
    const int n    = blk / (L_/QBLK);
    const int qb   = (blk % (L_/QBLK)) * QBLK;
    const int tid  = threadIdx.x;
    const int wave = tid >> 6;
    const int lane = tid & 63;
    const int lhi  = lane >> 4;    // 0..3
    const int llo  = lane & 15;

    const unsigned short* qtb = q_t + (size_t)n * L_ * CR_;
    const unsigned short* ktb = k_t + (size_t)n * L_ * CR_;
    const unsigned short* vb  = v   + (size_t)n * C_ * L_;

    // Q fragments (held all kernel): A-frag row = lane&15, k = (lane>>4)*8
    bf16x8 qf[2];
    {
        int row = qb + wave * 16 + llo;
        #pragma unroll
        for (int ks = 0; ks < 2; ks++)
            qf[ks] = *reinterpret_cast<const bf16x8*>(qtb + (size_t)row * CR_ + ks*32 + lhi*8);
    }

    f32x4 o_acc[8];
    #pragma unroll
    for (int ct = 0; ct < 8; ct++) o_acc[ct] = f32x4{0.f, 0.f, 0.f, 0.f};
    float m_run[4], l_run[4];
    #pragma unroll
    for (int r = 0; r < 4; r++) { m_run[r] = -INFINITY; l_run[r] = 0.f; }

    for (int jb = 0; jb < L_; jb += KVBLK) {
        __syncthreads();   // prior iteration's LDS reads complete
        // stage K tile: 8KB = 512 x 16B, 2 chunks/thread
        #pragma unroll
        for (int tt = 0; tt < 2; tt++) {
            int lin = (tid + tt*256) * 16;
            int row = lin >> 7;        // local j
            int col = lin & 127;       // byte within row
            bf16x8 src = *reinterpret_cast<const bf16x8*>(ktb + (size_t)(jb + row) * CR_ + (col >> 1));
            *reinterpret_cast<bf16x8*>(k_lds + row*128 + (col ^ ((row & 7) << 4))) = src;
        }
        // stage V tile: 16KB = 1024 x 16B, 4 chunks/thread
        #pragma unroll
        for (int tt = 0; tt < 4; tt++) {
            int lin = (tid + tt*256) * 16;
            int row = lin >> 7;        // c
            int col = lin & 127;       // byte (j-local * 2)
            bf16x8 src = *reinterpret_cast<const bf16x8*>(vb + (size_t)row * L_ + jb + (col >> 1));
            *reinterpret_cast<bf16x8*>(v_lds + row*128 + (col ^ ((row & 7) << 4))) = src;
        }
        __syncthreads();   // staging complete

        // ---- QK^T: S[16 rows x 64 cols] per wave ----
        f32x4 s[4];
        #pragma unroll
        for (int jt = 0; jt < 4; jt++) s[jt] = f32x4{0.f, 0.f, 0.f, 0.f};
        #pragma unroll
        for (int ks = 0; ks < 2; ks++) {
            #pragma unroll
            for (int jt = 0; jt < 4; jt++) {
                int row  = jt*16 + llo;
                int colb = ks*64 + lhi*16;
                bf16x8 kf = *reinterpret_cast<const bf16x8*>(
                    k_lds + row*128 + (colb ^ ((row & 7) << 4)));
                s[jt] = __builtin_amdgcn_mfma_f32_16x16x32_bf16(qf[ks], kf, s[jt], 0, 0, 0);
            }
        }

        // ---- online softmax ----
        float scale[4];
        #pragma unroll
        for (int r = 0; r < 4; r++) {
            float m = fmaxf(fmaxf(s[0][r], s[1][r]), fmaxf(s[2][r], s[3][r]));
            #pragma unroll
            for (int msk = 1; msk < 16; msk <<= 1)
                m = fmaxf(m, __shfl_xor(m, msk, 64));
            float mn = fmaxf(m_run[r], m);
            scale[r] = __expf(m_run[r] - mn);
            m_run[r] = mn;
        }
        #pragma unroll
        for (int ct = 0; ct < 8; ct++) {
            #pragma unroll
            for (int r = 0; r < 4; r++) o_acc[ct][r] *= scale[r];
        }
        // P = exp(S - m), row sums, stage P (bf16, per-wave region, no barrier needed)
        #pragma unroll
        for (int r = 0; r < 4; r++) {
            int prow = wave*16 + lhi*4 + r;
            float rs = 0.f;
            #pragma unroll
            for (int jt = 0; jt < 4; jt++) {
                float p = __expf(s[jt][r] - m_run[r]);
                rs += p;
                int colb = (jt*16 + llo) * 2;
                *reinterpret_cast<unsigned short*>(
                    p_lds + prow*128 + (colb ^ ((prow & 7) << 4))) = f2bf(p);
            }
            #pragma unroll
            for (int msk = 1; msk < 16; msk <<= 1)
                rs += __shfl_xor(rs, msk, 64);
            l_run[r] = l_run[r] * scale[r] + rs;
        }

        // ---- PV: O[16 rows x 128 c] += P[16x64] @ V[64x128] ----
        #pragma unroll
        for (int ks = 0; ks < 2; ks++) {
            int prow = wave*16 + llo;
            int colb = ks*64 + lhi*16;
            bf16x8 pf = *reinterpret_cast<const bf16x8*>(
                p_lds + prow*128 + (colb ^ ((prow & 7) << 4)));
            #pragma unroll
            for (int ct = 0; ct < 8; ct++) {
                int vrow = ct*16 + llo;
                bf16x8 vf = *reinterpret_cast<const bf16x8*>(
                    v_lds + vrow*128 + (colb ^ ((vrow & 7) << 4)));
                o_acc[ct] = __builtin_amdgcn_mfma_f32_16x16x32_bf16(pf, vf, o_acc[ct], 0, 0, 0);
            }
        }
    }

    // ---- epilogue: normalize, add residual, store ----
    const float* xb = x   + (size_t)n * C_ * L_;
    float*       ob = out + (size_t)n * C_ * L_;
    const int i0 = qb + wave*16 + lhi*4;
    float inv[4];
    #pragma unroll
    for (int r = 0; r < 4; r++) inv[r] = 1.0f / l_run[r];
    #pragma unroll
    for (int ct = 0; ct < 8; ct++) {
        int c = ct*16 + llo;
        const float4 xr = *reinterpret_cast<const float4*>(xb + (size_t)c * L_ + i0);
        float4 o4;
        o4.x = o_acc[ct][0] * inv[0] + xr.x;
        o4.y = o_acc[ct][1] * inv[1] + xr.y;
        o4.z = o_acc[ct][2] * inv[2] + xr.z;
        o4.w = o_acc[ct][3] * inv[3] + xr.w;
        *reinterpret_cast<float4*>(ob + (size_t)c * L_ + i0) = o4;
    }
}

extern "C" void kernel_launch(void* const* d_in, const int* in_sizes, int n_in,
                              void* d_out, int out_size, void* d_ws, size_t ws_size,
                              hipStream_t stream) {
    const float* x  = (const float*)d_in[0];
    const float* w1 = (const float*)d_in[1];
    const float* b1 = (const float*)d_in[2];
    const float* a1 = (const float*)d_in[3];
    const float* w2 = (const float*)d_in[4];
    const float* b2 = (const float*)d_in[5];
    const float* a2 = (const float*)d_in[6];
    const float* wa = (const float*)d_in[7];
    const float* ba = (const float*)d_in[8];
    const float* aa = (const float*)d_in[9];
    float* out = (float*)d_out;
    unsigned short* qkv = (unsigned short*)d_ws;   // q_t | k_t | v  (~9.44 MB)

    proj_kernel<<<N_ * (L_/16), 256, 0, stream>>>(x, w1, b1, a1, w2, b2, a2, wa, ba, aa, qkv);
    attn_kernel<<<N_ * (L_/QBLK), 256, 0, stream>>>(qkv, x, out);
}

// Round 2
// 238.519 us; speedup vs baseline: 1.4885x; 1.4885x over previous
//
#include <hip/hip_runtime.h>

#define N_  2
#define C_  128
#define CR_ 64
#define H_  96
#define W_  96
#define L_  (H_*W_)     // 9216
#define QBLK 64
#define KVBLK 64
#define NQT (L_/QBLK)   // 144
#define SMAX 8

typedef short bf16x8 __attribute__((ext_vector_type(8)));
typedef float f32x4  __attribute__((ext_vector_type(4)));

static __device__ __forceinline__ unsigned short f2bf(float f) {
    unsigned u = __builtin_bit_cast(unsigned, f);
    unsigned rounding = 0x7FFFu + ((u >> 16) & 1u);
    return (unsigned short)((u + rounding) >> 16);
}

// ---------------------------------------------------------------------------
// Projection kernel: q = prelu(W1 x + b1), k = prelu(W2 x + b2), v = prelu(Wa x + ba)
// Outputs (bf16, in d_ws):  q_t [N][L][CR], k_t [N][L][CR], v [N][C][L]
// ---------------------------------------------------------------------------
__global__ __launch_bounds__(256) void proj_kernel(
    const float* __restrict__ x,
    const float* __restrict__ w1, const float* __restrict__ b1, const float* __restrict__ a1,
    const float* __restrict__ w2, const float* __restrict__ b2, const float* __restrict__ a2,
    const float* __restrict__ wa, const float* __restrict__ ba, const float* __restrict__ aa,
    unsigned short* __restrict__ qkv)
{
    __shared__ float xs[C_][16];
    const int blk = blockIdx.x;                // 0 .. N*L/16-1
    const int n   = blk / (L_/16);
    const int i0  = (blk % (L_/16)) * 16;
    const float* xb = x + (size_t)n * C_ * L_;

    for (int idx = threadIdx.x; idx < C_*16; idx += 256) {
        int c = idx >> 4, j = idx & 15;
        xs[c][j] = xb[(size_t)c * L_ + i0 + j];
    }
    __syncthreads();

    const int t = threadIdx.x;
    const float* wrow;
    float bias, alpha;
    int o;
    if (t < 64)       { o = t;       wrow = w1 + o*C_; bias = b1[o]; alpha = a1[0]; }
    else if (t < 128) { o = t - 64;  wrow = w2 + o*C_; bias = b2[o]; alpha = a2[0]; }
    else              { o = t - 128; wrow = wa + o*C_; bias = ba[o]; alpha = aa[0]; }

    float acc[16];
    #pragma unroll
    for (int j = 0; j < 16; j++) acc[j] = bias;

    for (int c = 0; c < C_; c++) {
        float wv = wrow[c];
        #pragma unroll
        for (int j = 0; j < 16; j++) acc[j] += wv * xs[c][j];
    }

    unsigned short vals[16];
    #pragma unroll
    for (int j = 0; j < 16; j++) {
        float y = acc[j];
        y = fmaxf(y, 0.0f) + alpha * fminf(y, 0.0f);
        vals[j] = f2bf(y);
    }

    unsigned short* q_t = qkv;
    unsigned short* k_t = qkv + (size_t)N_ * L_ * CR_;
    unsigned short* v   = qkv + (size_t)2 * N_ * L_ * CR_;

    if (t < 64) {
        unsigned short* d = q_t + (size_t)n * L_ * CR_;
        #pragma unroll
        for (int j = 0; j < 16; j++) d[(size_t)(i0 + j) * CR_ + o] = vals[j];
    } else if (t < 128) {
        unsigned short* d = k_t + (size_t)n * L_ * CR_;
        #pragma unroll
        for (int j = 0; j < 16; j++) d[(size_t)(i0 + j) * CR_ + o] = vals[j];
    } else {
        unsigned short* d = v + (size_t)n * C_ * L_ + (size_t)o * L_ + i0;
        union { unsigned short u[8]; int4 v4; } p0, p1;
        #pragma unroll
        for (int j = 0; j < 8; j++) { p0.u[j] = vals[j]; p1.u[j] = vals[8 + j]; }
        *reinterpret_cast<int4*>(d)     = p0.v4;
        *reinterpret_cast<int4*>(d + 8) = p1.v4;
    }
}

// ---------------------------------------------------------------------------
// Split-K flash attention. Block = (n, q-tile, split). Each split covers
// TILES_PER KV tiles of 64. Writes partial O (f32) + per-row m, l to ws.
// ---------------------------------------------------------------------------
__global__ __launch_bounds__(256) void attn_kernel(
    const unsigned short* __restrict__ qkv,
    float* __restrict__ o_part,   // [N][NQT][S][C][QBLK]
    float* __restrict__ m_part,   // [N][NQT][S][QBLK]
    float* __restrict__ l_part,   // [N][NQT][S][QBLK]
    int S, int TILES_PER)
{
    __shared__ alignas(16) unsigned char k_lds[KVBLK * 128]; // [64 j][64 c] bf16, swizzled
    __shared__ alignas(16) unsigned char v_lds[C_ * 128];    // [128 c][64 j] bf16, swizzled
    __shared__ alignas(16) unsigned char p_lds[QBLK * 128];  // [64 i][64 j] bf16, swizzled

    const unsigned short* q_t = qkv;
    const unsigned short* k_t = qkv + (size_t)N_ * L_ * CR_;
    const unsigned short* v   = qkv + (size_t)2 * N_ * L_ * CR_;

    const int blk  = blockIdx.x;
    const int n    = blk / (NQT * S);
    const int rem  = blk % (NQT * S);
    const int qbi  = rem / S;
    const int s    = rem % S;
    const int qb   = qbi * QBLK;
    const int tid  = threadIdx.x;
    const int wave = tid >> 6;
    const int lane = tid & 63;
    const int lhi  = lane >> 4;    // 0..3
    const int llo  = lane & 15;

    const int jb_beg = s * TILES_PER * KVBLK;
    const int jb_end = min(L_, jb_beg + TILES_PER * KVBLK);

    const unsigned short* qtb = q_t + (size_t)n * L_ * CR_;
    const unsigned short* ktb = k_t + (size_t)n * L_ * CR_;
    const unsigned short* vb  = v   + (size_t)n * C_ * L_;

    bf16x8 qf[2];
    {
        int row = qb + wave * 16 + llo;
        #pragma unroll
        for (int ks = 0; ks < 2; ks++)
            qf[ks] = *reinterpret_cast<const bf16x8*>(qtb + (size_t)row * CR_ + ks*32 + lhi*8);
    }

    f32x4 o_acc[8];
    #pragma unroll
    for (int ct = 0; ct < 8; ct++) o_acc[ct] = f32x4{0.f, 0.f, 0.f, 0.f};
    float m_run[4], l_run[4];
    #pragma unroll
    for (int r = 0; r < 4; r++) { m_run[r] = -INFINITY; l_run[r] = 0.f; }

    for (int jb = jb_beg; jb < jb_end; jb += KVBLK) {
        __syncthreads();
        // stage K tile: 8KB
        #pragma unroll
        for (int tt = 0; tt < 2; tt++) {
            int lin = (tid + tt*256) * 16;
            int row = lin >> 7;
            int col = lin & 127;
            bf16x8 src = *reinterpret_cast<const bf16x8*>(ktb + (size_t)(jb + row) * CR_ + (col >> 1));
            *reinterpret_cast<bf16x8*>(k_lds + row*128 + (col ^ ((row & 7) << 4))) = src;
        }
        // stage V tile: 16KB
        #pragma unroll
        for (int tt = 0; tt < 4; tt++) {
            int lin = (tid + tt*256) * 16;
            int row = lin >> 7;
            int col = lin & 127;
            bf16x8 src = *reinterpret_cast<const bf16x8*>(vb + (size_t)row * L_ + jb + (col >> 1));
            *reinterpret_cast<bf16x8*>(v_lds + row*128 + (col ^ ((row & 7) << 4))) = src;
        }
        __syncthreads();

        // ---- QK^T ----
        f32x4 sacc[4];
        #pragma unroll
        for (int jt = 0; jt < 4; jt++) sacc[jt] = f32x4{0.f, 0.f, 0.f, 0.f};
        #pragma unroll
        for (int ks = 0; ks < 2; ks++) {
            #pragma unroll
            for (int jt = 0; jt < 4; jt++) {
                int row  = jt*16 + llo;
                int colb = ks*64 + lhi*16;
                bf16x8 kf = *reinterpret_cast<const bf16x8*>(
                    k_lds + row*128 + (colb ^ ((row & 7) << 4)));
                sacc[jt] = __builtin_amdgcn_mfma_f32_16x16x32_bf16(qf[ks], kf, sacc[jt], 0, 0, 0);
            }
        }

        // ---- online softmax ----
        float scale[4];
        bool grow = false;
        #pragma unroll
        for (int r = 0; r < 4; r++) {
            float m = fmaxf(fmaxf(sacc[0][r], sacc[1][r]), fmaxf(sacc[2][r], sacc[3][r]));
            #pragma unroll
            for (int msk = 1; msk < 16; msk <<= 1)
                m = fmaxf(m, __shfl_xor(m, msk, 64));
            float mn = fmaxf(m_run[r], m);
            scale[r] = __expf(m_run[r] - mn);
            m_run[r] = mn;
            grow = grow || (scale[r] != 1.0f);
        }
        if (__any(grow)) {            // skip exact-identity rescale (scale==1)
            #pragma unroll
            for (int ct = 0; ct < 8; ct++) {
                #pragma unroll
                for (int r = 0; r < 4; r++) o_acc[ct][r] *= scale[r];
            }
        }
        #pragma unroll
        for (int r = 0; r < 4; r++) {
            int prow = wave*16 + lhi*4 + r;
            float rs = 0.f;
            #pragma unroll
            for (int jt = 0; jt < 4; jt++) {
                float p = __expf(sacc[jt][r] - m_run[r]);
                rs += p;
                int colb = (jt*16 + llo) * 2;
                *reinterpret_cast<unsigned short*>(
                    p_lds + prow*128 + (colb ^ ((prow & 7) << 4))) = f2bf(p);
            }
            #pragma unroll
            for (int msk = 1; msk < 16; msk <<= 1)
                rs += __shfl_xor(rs, msk, 64);
            l_run[r] = l_run[r] * scale[r] + rs;
        }

        // ---- PV ----
        #pragma unroll
        for (int ks = 0; ks < 2; ks++) {
            int prow = wave*16 + llo;
            int colb = ks*64 + lhi*16;
            bf16x8 pf = *reinterpret_cast<const bf16x8*>(
                p_lds + prow*128 + (colb ^ ((prow & 7) << 4)));
            #pragma unroll
            for (int ct = 0; ct < 8; ct++) {
                int vrow = ct*16 + llo;
                bf16x8 vf = *reinterpret_cast<const bf16x8*>(
                    v_lds + vrow*128 + (colb ^ ((vrow & 7) << 4)));
                o_acc[ct] = __builtin_amdgcn_mfma_f32_16x16x32_bf16(pf, vf, o_acc[ct], 0, 0, 0);
            }
        }
    }

    // ---- write partials ----
    float* ob = o_part + ((size_t)(n*NQT + qbi)*S + s) * (C_*QBLK);
    const int il0 = wave*16 + lhi*4;
    #pragma unroll
    for (int ct = 0; ct < 8; ct++) {
        int c = ct*16 + llo;
        float4 o4 = { o_acc[ct][0], o_acc[ct][1], o_acc[ct][2], o_acc[ct][3] };
        *reinterpret_cast<float4*>(ob + (size_t)c * QBLK + il0) = o4;
    }
    if (llo == 0) {
        float* mb = m_part + ((size_t)(n*NQT + qbi)*S + s) * QBLK;
        float* lb = l_part + ((size_t)(n*NQT + qbi)*S + s) * QBLK;
        #pragma unroll
        for (int r = 0; r < 4; r++) {
            mb[il0 + r] = m_run[r];
            lb[il0 + r] = l_run[r];
        }
    }
}

// ---------------------------------------------------------------------------
// Combine kernel: out[n][c][i] = (sum_s O_s * exp(m_s-M)) / (sum_s l_s*exp(m_s-M)) + x
// Block = (n, q-tile, c-chunk of 32). 256 threads, 8 f32 outputs each.
// ---------------------------------------------------------------------------
__global__ __launch_bounds__(256) void combine_kernel(
    const float* __restrict__ o_part,
    const float* __restrict__ m_part,
    const float* __restrict__ l_part,
    const float* __restrict__ x,
    float* __restrict__ out,
    int S)
{
    __shared__ float wls[SMAX][QBLK];
    __shared__ float invl[QBLK];

    const int blk = blockIdx.x;
    const int cc  = blk & 3;                 // c chunk (32)
    const int qbi = (blk >> 2) % NQT;
    const int n   = blk / (4 * NQT);
    const int tid = threadIdx.x;

    const size_t pbase = (size_t)(n*NQT + qbi) * S;

    if (tid < QBLK) {
        float m[SMAX], l[SMAX];
        float M = -INFINITY;
        for (int s = 0; s < S; s++) {
            m[s] = m_part[(pbase + s) * QBLK + tid];
            l[s] = l_part[(pbase + s) * QBLK + tid];
            M = fmaxf(M, m[s]);
        }
        float lt = 0.f;
        for (int s = 0; s < S; s++) {
            float w = __expf(m[s] - M);
            wls[s][tid] = w;
            lt += w * l[s];
        }
        invl[tid] = 1.0f / lt;
    }
    __syncthreads();

    const float* xb = x   + (size_t)n * C_ * L_;
    float*       ob = out + (size_t)n * C_ * L_;

    #pragma unroll
    for (int k = 0; k < 2; k++) {
        int item   = tid + k*256;
        int cl     = item >> 4;              // 0..31
        int il     = (item & 15) * 4;        // 0..60
        int c      = cc*32 + cl;
        int ig     = qbi*QBLK + il;

        float4 acc = {0.f, 0.f, 0.f, 0.f};
        for (int s = 0; s < S; s++) {
            const float4 o4 = *reinterpret_cast<const float4*>(
                o_part + (pbase + s) * (C_*QBLK) + (size_t)c * QBLK + il);
            acc.x += o4.x * wls[s][il+0];
            acc.y += o4.y * wls[s][il+1];
            acc.z += o4.z * wls[s][il+2];
            acc.w += o4.w * wls[s][il+3];
        }
        const float4 xr = *reinterpret_cast<const float4*>(xb + (size_t)c * L_ + ig);
        float4 r;
        r.x = acc.x * invl[il+0] + xr.x;
        r.y = acc.y * invl[il+1] + xr.y;
        r.z = acc.z * invl[il+2] + xr.z;
        r.w = acc.w * invl[il+3] + xr.w;
        *reinterpret_cast<float4*>(ob + (size_t)c * L_ + ig) = r;
    }
}

extern "C" void kernel_launch(void* const* d_in, const int* in_sizes, int n_in,
                              void* d_out, int out_size, void* d_ws, size_t ws_size,
                              hipStream_t stream) {
    const float* x  = (const float*)d_in[0];
    const float* w1 = (const float*)d_in[1];
    const float* b1 = (const float*)d_in[2];
    const float* a1 = (const float*)d_in[3];
    const float* w2 = (const float*)d_in[4];
    const float* b2 = (const float*)d_in[5];
    const float* a2 = (const float*)d_in[6];
    const float* wa = (const float*)d_in[7];
    const float* ba = (const float*)d_in[8];
    const float* aa = (const float*)d_in[9];
    float* out = (float*)d_out;

    unsigned short* qkv = (unsigned short*)d_ws;   // 9.44 MB
    size_t qkv_bytes = ((size_t)2*N_*L_*CR_ + (size_t)N_*C_*L_) * 2;
    size_t off = (qkv_bytes + 255) & ~(size_t)255;

    // pick largest split count S<=8 that fits in ws (deterministic: ws_size fixed)
    int S = SMAX;
    while (S > 1) {
        size_t need = off + (size_t)N_*NQT*S * ((size_t)C_*QBLK*4 + 2*QBLK*4);
        if (need <= ws_size) break;
        S--;
    }
    float* o_part = (float*)((char*)d_ws + off);
    float* m_part = o_part + (size_t)N_*NQT*S*C_*QBLK;
    float* l_part = m_part + (size_t)N_*NQT*S*QBLK;
    int tiles_per = (NQT/ (QBLK/KVBLK) * 1, (L_/KVBLK + S - 1) / S);

    proj_kernel<<<N_ * (L_/16), 256, 0, stream>>>(x, w1, b1, a1, w2, b2, a2, wa, ba, aa, qkv);
    attn_kernel<<<N_ * NQT * S, 256, 0, stream>>>(qkv, o_part, m_part, l_part, S, tiles_per);
    combine_kernel<<<N_ * NQT * 4, 256, 0, stream>>>(o_part, m_part, l_part, x, out, S);
}

// Round 4
// 149.950 us; speedup vs baseline: 2.3677x; 1.5907x over previous
//
#include <hip/hip_runtime.h>

#define N_  2
#define C_  128
#define CR_ 64
#define H_  96
#define W_  96
#define L_  (H_*W_)     // 9216
#define QBLK 64
#define KVBLK 64
#define NQT (L_/QBLK)   // 144
#define SMAX 8

typedef short bf16x8 __attribute__((ext_vector_type(8)));
typedef float f32x4  __attribute__((ext_vector_type(4)));

static __device__ __forceinline__ unsigned short f2bf(float f) {
    unsigned u = __builtin_bit_cast(unsigned, f);
    unsigned rounding = 0x7FFFu + ((u >> 16) & 1u);
    return (unsigned short)((u + rounding) >> 16);
}

static __device__ __forceinline__ unsigned pack_bf16(float lo, float hi) {
    return (unsigned)f2bf(lo) | ((unsigned)f2bf(hi) << 16);
}

// K-row permutation: rho bits [ks][e4][lhi1][lhi0][r1][r0] -> [ks][lhi1][lhi0][e4][r1][r0]
static __device__ __forceinline__ int sigma_(int r) {
    return (r & 0x23) | ((r & 0x0C) << 1) | ((r & 0x10) >> 2);
}

#define GLD16(G, Ld) __builtin_amdgcn_global_load_lds( \
    (const __attribute__((address_space(1))) void*)(G), \
    (__attribute__((address_space(3))) void*)(Ld), 16, 0, 0)

// ---------------------------------------------------------------------------
// Projection kernel: q_t [N][L][CR], k_t [N][L][CR], v [N][C][L] (bf16)
// ---------------------------------------------------------------------------
__global__ __launch_bounds__(256) void proj_kernel(
    const float* __restrict__ x,
    const float* __restrict__ w1, const float* __restrict__ b1, const float* __restrict__ a1,
    const float* __restrict__ w2, const float* __restrict__ b2, const float* __restrict__ a2,
    const float* __restrict__ wa, const float* __restrict__ ba, const float* __restrict__ aa,
    unsigned short* __restrict__ qkv)
{
    __shared__ float xs[C_][16];
    const int blk = blockIdx.x;
    const int n   = blk / (L_/16);
    const int i0  = (blk % (L_/16)) * 16;
    const float* xb = x + (size_t)n * C_ * L_;

    for (int idx = threadIdx.x; idx < C_*16; idx += 256) {
        int c = idx >> 4, j = idx & 15;
        xs[c][j] = xb[(size_t)c * L_ + i0 + j];
    }
    __syncthreads();

    const int t = threadIdx.x;
    const float* wrow;
    float bias, alpha;
    int o;
    if (t < 64)       { o = t;       wrow = w1 + o*C_; bias = b1[o]; alpha = a1[0]; }
    else if (t < 128) { o = t - 64;  wrow = w2 + o*C_; bias = b2[o]; alpha = a2[0]; }
    else              { o = t - 128; wrow = wa + o*C_; bias = ba[o]; alpha = aa[0]; }

    float acc[16];
    #pragma unroll
    for (int j = 0; j < 16; j++) acc[j] = bias;

    for (int c = 0; c < C_; c++) {
        float wv = wrow[c];
        #pragma unroll
        for (int j = 0; j < 16; j++) acc[j] += wv * xs[c][j];
    }

    unsigned short vals[16];
    #pragma unroll
    for (int j = 0; j < 16; j++) {
        float y = acc[j];
        y = fmaxf(y, 0.0f) + alpha * fminf(y, 0.0f);
        vals[j] = f2bf(y);
    }

    unsigned short* q_t = qkv;
    unsigned short* k_t = qkv + (size_t)N_ * L_ * CR_;
    unsigned short* v   = qkv + (size_t)2 * N_ * L_ * CR_;

    if (t < 64) {
        unsigned short* d = q_t + (size_t)n * L_ * CR_;
        #pragma unroll
        for (int j = 0; j < 16; j++) d[(size_t)(i0 + j) * CR_ + o] = vals[j];
    } else if (t < 128) {
        unsigned short* d = k_t + (size_t)n * L_ * CR_;
        #pragma unroll
        for (int j = 0; j < 16; j++) d[(size_t)(i0 + j) * CR_ + o] = vals[j];
    } else {
        unsigned short* d = v + (size_t)n * C_ * L_ + (size_t)o * L_ + i0;
        union { unsigned short u[8]; int4 v4; } p0, p1;
        #pragma unroll
        for (int j = 0; j < 8; j++) { p0.u[j] = vals[j]; p1.u[j] = vals[8 + j]; }
        *reinterpret_cast<int4*>(d)     = p0.v4;
        *reinterpret_cast<int4*>(d + 8) = p1.v4;
    }
}

// ---------------------------------------------------------------------------
// Split-K flash attention, swapped-operand MFMA, in-register P, async staging.
// LDS per buffer: K [64 rho][64 c] bf16 (sigma-permuted rows, XOR-swizzled),
//                 V [128 c][64 j] bf16 (XOR-swizzled). Double buffered.
// ---------------------------------------------------------------------------
__global__ __launch_bounds__(256, 3) void attn_kernel(
    const unsigned short* __restrict__ qkv,
    float* __restrict__ o_part,   // [N][NQT][S][C][QBLK]
    float* __restrict__ m_part,   // [N][NQT][S][QBLK]
    float* __restrict__ l_part,   // [N][NQT][S][QBLK]
    int S, int TILES_PER)
{
    __shared__ alignas(16) unsigned char kv_lds[2][24*1024];

    const unsigned short* q_t = qkv;
    const unsigned short* k_t = qkv + (size_t)N_ * L_ * CR_;
    const unsigned short* v   = qkv + (size_t)2 * N_ * L_ * CR_;

    const int blk  = blockIdx.x;
    const int n    = blk / (NQT * S);
    const int rem  = blk % (NQT * S);
    const int qbi  = rem / S;
    const int s    = rem % S;
    const int qb   = qbi * QBLK;
    const int tid  = threadIdx.x;
    const int wave = tid >> 6;
    const int lane = tid & 63;
    const int lhi  = lane >> 4;    // 0..3
    const int llo  = lane & 15;    // = q-row i within wave

    const int jb_beg = s * TILES_PER * KVBLK;
    const int jb_end = min(L_, jb_beg + TILES_PER * KVBLK);

    const unsigned short* qtb = q_t + (size_t)n * L_ * CR_;
    const unsigned short* ktb = k_t + (size_t)n * L_ * CR_;
    const unsigned short* vb  = v   + (size_t)n * C_ * L_;

    // Q B-fragments (col=llo -> q-row, k=lhi*8+e -> c)
    bf16x8 qf[2];
    {
        int row = qb + wave * 16 + llo;
        #pragma unroll
        for (int ks = 0; ks < 2; ks++)
            qf[ks] = *reinterpret_cast<const bf16x8*>(qtb + (size_t)row * CR_ + ks*32 + lhi*8);
    }

    // staging source addresses (pre-swizzled global, linear LDS dest)
    const int l8 = lane >> 3;          // row-within-segment 0..7
    const int l7 = (lane & 7) * 16;    // byte chunk within 128B row
    const int rho0 = wave*16 + l8;
    const int rho1 = rho0 + 8;
    const unsigned short* kbase0 = ktb + (size_t)sigma_(rho0) * CR_ + ((l7 ^ ((rho0 & 7) << 4)) >> 1);
    const unsigned short* kbase1 = ktb + (size_t)sigma_(rho1) * CR_ + ((l7 ^ ((rho1 & 7) << 4)) >> 1);
    const unsigned short* vbase[4];
    #pragma unroll
    for (int t = 0; t < 4; t++) {
        int c = wave*32 + t*8 + l8;
        vbase[t] = vb + (size_t)c * L_ + ((l7 ^ (l8 << 4)) >> 1);
    }

    #define STAGE(b, jb_) do {                                                   \
        GLD16(kbase0 + (size_t)(jb_) * CR_, &kv_lds[b][(wave*2+0)*1024 + 0]);    \
        GLD16(kbase1 + (size_t)(jb_) * CR_, &kv_lds[b][(wave*2+1)*1024 + 0]);    \
        GLD16(vbase[0] + (jb_), &kv_lds[b][8192 + (wave*4+0)*1024]);             \
        GLD16(vbase[1] + (jb_), &kv_lds[b][8192 + (wave*4+1)*1024]);             \
        GLD16(vbase[2] + (jb_), &kv_lds[b][8192 + (wave*4+2)*1024]);             \
        GLD16(vbase[3] + (jb_), &kv_lds[b][8192 + (wave*4+3)*1024]);             \
    } while (0)

    f32x4 o_acc[8];
    #pragma unroll
    for (int ct = 0; ct < 8; ct++) o_acc[ct] = f32x4{0.f, 0.f, 0.f, 0.f};
    float m_run = -INFINITY, l_run = 0.f;

    int cur = 0;
    STAGE(0, jb_beg);
    __syncthreads();

    for (int jb = jb_beg; jb < jb_end; jb += KVBLK) {
        if (jb + KVBLK < jb_end) STAGE(cur ^ 1, jb + KVBLK);

        const unsigned char* kbuf = &kv_lds[cur][0];
        const unsigned char* vbuf = &kv_lds[cur][8192];

        // ---- S^T = K . Q^T : sacc[jt][r] = S(i=llo, k-lds-row jt*16+lhi*4+r) ----
        f32x4 sacc[4];
        #pragma unroll
        for (int jt = 0; jt < 4; jt++) sacc[jt] = f32x4{0.f, 0.f, 0.f, 0.f};
        #pragma unroll
        for (int ks = 0; ks < 2; ks++) {
            #pragma unroll
            for (int jt = 0; jt < 4; jt++) {
                int rho  = jt*16 + llo;
                int colb = ks*64 + lhi*16;
                bf16x8 kf = *reinterpret_cast<const bf16x8*>(
                    kbuf + rho*128 + (colb ^ ((rho & 7) << 4)));
                sacc[jt] = __builtin_amdgcn_mfma_f32_16x16x32_bf16(kf, qf[ks], sacc[jt], 0, 0, 0);
            }
        }

        // ---- online softmax (per-lane row i=llo; reduce over lhi only) ----
        float tm = sacc[0][0];
        #pragma unroll
        for (int jt = 0; jt < 4; jt++) {
            #pragma unroll
            for (int r = 0; r < 4; r++) tm = fmaxf(tm, sacc[jt][r]);
        }
        tm = fmaxf(tm, __shfl_xor(tm, 16, 64));
        tm = fmaxf(tm, __shfl_xor(tm, 32, 64));
        if (!__all(tm <= m_run + 8.f)) {      // defer-max THR=8
            float mn = fmaxf(m_run, tm);
            float sc = __expf(m_run - mn);
            #pragma unroll
            for (int ct = 0; ct < 8; ct++) {
                #pragma unroll
                for (int r = 0; r < 4; r++) o_acc[ct][r] *= sc;
            }
            l_run *= sc;
            m_run = mn;
        }
        float p[4][4];
        float rs = 0.f;
        #pragma unroll
        for (int jt = 0; jt < 4; jt++) {
            #pragma unroll
            for (int r = 0; r < 4; r++) {
                p[jt][r] = __expf(sacc[jt][r] - m_run);
                rs += p[jt][r];
            }
        }
        rs += __shfl_xor(rs, 16, 64);
        rs += __shfl_xor(rs, 32, 64);
        l_run += rs;

        // pack P -> B-frags (no cross-lane movement thanks to sigma-permuted K)
        unsigned pk[8];
        #pragma unroll
        for (int jt = 0; jt < 4; jt++) {
            pk[jt*2 + 0] = pack_bf16(p[jt][0], p[jt][1]);
            pk[jt*2 + 1] = pack_bf16(p[jt][2], p[jt][3]);
        }

        // ---- O^T += V^T . P^T ----
        #pragma unroll
        for (int ks = 0; ks < 2; ks++) {
            bf16x8 pf = *reinterpret_cast<const bf16x8*>(&pk[4*ks]);
            #pragma unroll
            for (int ct = 0; ct < 8; ct++) {
                int c = ct*16 + llo;
                int colb = ks*64 + lhi*16;
                bf16x8 vf = *reinterpret_cast<const bf16x8*>(
                    vbuf + c*128 + (colb ^ ((c & 7) << 4)));
                o_acc[ct] = __builtin_amdgcn_mfma_f32_16x16x32_bf16(vf, pf, o_acc[ct], 0, 0, 0);
            }
        }

        __syncthreads();   // drains this wave's prefetch (implicit vmcnt(0)) + buffer handoff
        cur ^= 1;
    }

    // ---- write partials: o_acc[ct][r] = O[c=ct*16+lhi*4+r][i=llo] ----
    float* ob = o_part + ((size_t)(n*NQT + qbi)*S + s) * (C_*QBLK);
    const int i_loc = wave*16 + llo;
    #pragma unroll
    for (int ct = 0; ct < 8; ct++) {
        #pragma unroll
        for (int r = 0; r < 4; r++) {
            int c = ct*16 + lhi*4 + r;
            ob[(size_t)c * QBLK + i_loc] = o_acc[ct][r];
        }
    }
    if (lhi == 0) {
        float* mb = m_part + ((size_t)(n*NQT + qbi)*S + s) * QBLK;
        float* lb = l_part + ((size_t)(n*NQT + qbi)*S + s) * QBLK;
        mb[i_loc] = m_run;
        lb[i_loc] = l_run;
    }
    #undef STAGE
}

// ---------------------------------------------------------------------------
// Combine kernel
// ---------------------------------------------------------------------------
__global__ __launch_bounds__(256) void combine_kernel(
    const float* __restrict__ o_part,
    const float* __restrict__ m_part,
    const float* __restrict__ l_part,
    const float* __restrict__ x,
    float* __restrict__ out,
    int S)
{
    __shared__ float wls[SMAX][QBLK];
    __shared__ float invl[QBLK];

    const int blk = blockIdx.x;
    const int cc  = blk & 3;
    const int qbi = (blk >> 2) % NQT;
    const int n   = blk / (4 * NQT);
    const int tid = threadIdx.x;

    const size_t pbase = (size_t)(n*NQT + qbi) * S;

    if (tid < QBLK) {
        float m[SMAX], l[SMAX];
        float M = -INFINITY;
        for (int s = 0; s < S; s++) {
            m[s] = m_part[(pbase + s) * QBLK + tid];
            l[s] = l_part[(pbase + s) * QBLK + tid];
            M = fmaxf(M, m[s]);
        }
        float lt = 0.f;
        for (int s = 0; s < S; s++) {
            float w = __expf(m[s] - M);
            wls[s][tid] = w;
            lt += w * l[s];
        }
        invl[tid] = 1.0f / lt;
    }
    __syncthreads();

    const float* xb = x   + (size_t)n * C_ * L_;
    float*       ob = out + (size_t)n * C_ * L_;

    #pragma unroll
    for (int k = 0; k < 2; k++) {
        int item   = tid + k*256;
        int cl     = item >> 4;
        int il     = (item & 15) * 4;
        int c      = cc*32 + cl;
        int ig     = qbi*QBLK + il;

        float4 acc = {0.f, 0.f, 0.f, 0.f};
        for (int s = 0; s < S; s++) {
            const float4 o4 = *reinterpret_cast<const float4*>(
                o_part + (pbase + s) * (C_*QBLK) + (size_t)c * QBLK + il);
            acc.x += o4.x * wls[s][il+0];
            acc.y += o4.y * wls[s][il+1];
            acc.z += o4.z * wls[s][il+2];
            acc.w += o4.w * wls[s][il+3];
        }
        const float4 xr = *reinterpret_cast<const float4*>(xb + (size_t)c * L_ + ig);
        float4 r;
        r.x = acc.x * invl[il+0] + xr.x;
        r.y = acc.y * invl[il+1] + xr.y;
        r.z = acc.z * invl[il+2] + xr.z;
        r.w = acc.w * invl[il+3] + xr.w;
        *reinterpret_cast<float4*>(ob + (size_t)c * L_ + ig) = r;
    }
}

extern "C" void kernel_launch(void* const* d_in, const int* in_sizes, int n_in,
                              void* d_out, int out_size, void* d_ws, size_t ws_size,
                              hipStream_t stream) {
    const float* x  = (const float*)d_in[0];
    const float* w1 = (const float*)d_in[1];
    const float* b1 = (const float*)d_in[2];
    const float* a1 = (const float*)d_in[3];
    const float* w2 = (const float*)d_in[4];
    const float* b2 = (const float*)d_in[5];
    const float* a2 = (const float*)d_in[6];
    const float* wa = (const float*)d_in[7];
    const float* ba = (const float*)d_in[8];
    const float* aa = (const float*)d_in[9];
    float* out = (float*)d_out;

    unsigned short* qkv = (unsigned short*)d_ws;
    size_t qkv_bytes = ((size_t)2*N_*L_*CR_ + (size_t)N_*C_*L_) * 2;
    size_t off = (qkv_bytes + 255) & ~(size_t)255;

    int S = SMAX;
    while (S > 1) {
        size_t need = off + (size_t)N_*NQT*S * ((size_t)C_*QBLK*4 + 2*QBLK*4);
        if (need <= ws_size) break;
        S--;
    }
    float* o_part = (float*)((char*)d_ws + off);
    float* m_part = o_part + (size_t)N_*NQT*S*C_*QBLK;
    float* l_part = m_part + (size_t)N_*NQT*S*QBLK;
    int tiles_per = (L_/KVBLK + S - 1) / S;

    proj_kernel<<<N_ * (L_/16), 256, 0, stream>>>(x, w1, b1, a1, w2, b2, a2, wa, ba, aa, qkv);
    attn_kernel<<<N_ * NQT * S, 256, 0, stream>>>(qkv, o_part, m_part, l_part, S, tiles_per);
    combine_kernel<<<N_ * NQT * 4, 256, 0, stream>>>(o_part, m_part, l_part, x, out, S);
}

// Round 6
// 139.818 us; speedup vs baseline: 2.5393x; 1.0725x over previous
//
#include <hip/hip_runtime.h>

#define N_  2
#define C_  128
#define CR_ 64
#define H_  96
#define W_  96
#define L_  (H_*W_)     // 9216
#define QBLK 128        // q-rows per block (4 waves x 32 rows)
#define KVBLK 64
#define NQB (L_/QBLK)   // 72
#define SMAX 8
#define LOG2E 1.44269504088896f

typedef short bf16x8 __attribute__((ext_vector_type(8)));
typedef float f32x4  __attribute__((ext_vector_type(4)));

static __device__ __forceinline__ float exp2_fast(float x) {
    return __builtin_amdgcn_exp2f(x);
}

static __device__ __forceinline__ unsigned short f2bf(float f) {
    unsigned u = __builtin_bit_cast(unsigned, f);
    unsigned rounding = 0x7FFFu + ((u >> 16) & 1u);
    return (unsigned short)((u + rounding) >> 16);
}

static __device__ __forceinline__ unsigned cvt_pk_bf16(float lo, float hi) {
    unsigned r;
    asm("v_cvt_pk_bf16_f32 %0, %1, %2" : "=v"(r) : "v"(lo), "v"(hi));
    return r;
}

static __device__ __forceinline__ float bf2f(unsigned short s) {
    return __builtin_bit_cast(float, ((unsigned)s) << 16);
}

// K-row permutation: rho bits [ks][e4][lhi1][lhi0][r1][r0] -> [ks][lhi1][lhi0][e4][r1][r0]
static __device__ __forceinline__ int sigma_(int r) {
    return (r & 0x23) | ((r & 0x0C) << 1) | ((r & 0x10) >> 2);
}

#define GLD16(G, Ld) __builtin_amdgcn_global_load_lds( \
    (const __attribute__((address_space(1))) void*)(G), \
    (__attribute__((address_space(3))) void*)(Ld), 16, 0, 0)

// ---------------------------------------------------------------------------
// Projection: q = prelu(W1 x + b1) * LOG2E, k = prelu(W2 x + b2), v = prelu(Wa x + ba)
// Outputs (bf16): q_t [N][L][CR], k_t [N][L][CR], v [N][C][L]. 32 positions/block.
// ---------------------------------------------------------------------------
__global__ __launch_bounds__(256) void proj_kernel(
    const float* __restrict__ x,
    const float* __restrict__ w1, const float* __restrict__ b1, const float* __restrict__ a1,
    const float* __restrict__ w2, const float* __restrict__ b2, const float* __restrict__ a2,
    const float* __restrict__ wa, const float* __restrict__ ba, const float* __restrict__ aa,
    unsigned short* __restrict__ qkv)
{
    __shared__ float xs[C_][32];
    const int blk = blockIdx.x;                // 0 .. N*L/32-1
    const int n   = blk / (L_/32);
    const int i0  = (blk % (L_/32)) * 32;
    const float* xb = x + (size_t)n * C_ * L_;

    #pragma unroll
    for (int k = 0; k < 4; k++) {
        int idx = threadIdx.x + k*256;         // float4 granules: 128c x 8 groups
        int c = idx >> 3, j0 = (idx & 7) * 4;
        *reinterpret_cast<float4*>(&xs[c][j0]) =
            *reinterpret_cast<const float4*>(xb + (size_t)c * L_ + i0 + j0);
    }
    __syncthreads();

    const int t = threadIdx.x;
    const float* wrow;
    float bias, alpha, oscale;
    int o;
    if (t < 64)       { o = t;       wrow = w1 + o*C_; bias = b1[o]; alpha = a1[0]; oscale = LOG2E; }
    else if (t < 128) { o = t - 64;  wrow = w2 + o*C_; bias = b2[o]; alpha = a2[0]; oscale = 1.0f; }
    else              { o = t - 128; wrow = wa + o*C_; bias = ba[o]; alpha = aa[0]; oscale = 1.0f; }

    float acc[32];
    #pragma unroll
    for (int j = 0; j < 32; j++) acc[j] = bias;

    for (int c = 0; c < C_; c++) {
        float wv = wrow[c];
        #pragma unroll
        for (int j = 0; j < 32; j++) acc[j] += wv * xs[c][j];
    }

    unsigned short vals[32];
    #pragma unroll
    for (int j = 0; j < 32; j++) {
        float y = acc[j];
        y = (fmaxf(y, 0.0f) + alpha * fminf(y, 0.0f)) * oscale;
        vals[j] = f2bf(y);
    }

    unsigned short* q_t = qkv;
    unsigned short* k_t = qkv + (size_t)N_ * L_ * CR_;
    unsigned short* v   = qkv + (size_t)2 * N_ * L_ * CR_;

    if (t < 64) {
        unsigned short* d = q_t + (size_t)n * L_ * CR_;
        #pragma unroll
        for (int j = 0; j < 32; j++) d[(size_t)(i0 + j) * CR_ + o] = vals[j];
    } else if (t < 128) {
        unsigned short* d = k_t + (size_t)n * L_ * CR_;
        #pragma unroll
        for (int j = 0; j < 32; j++) d[(size_t)(i0 + j) * CR_ + o] = vals[j];
    } else {
        unsigned short* d = v + (size_t)n * C_ * L_ + (size_t)o * L_ + i0;
        #pragma unroll
        for (int g = 0; g < 4; g++) {
            union { unsigned short u[8]; int4 v4; } p;
            #pragma unroll
            for (int j = 0; j < 8; j++) p.u[j] = vals[g*8 + j];
            *reinterpret_cast<int4*>(d + g*8) = p.v4;
        }
    }
}

// ---------------------------------------------------------------------------
// Split-K flash attention. 4 waves x 32 q-rows (2 sub-tiles of 16). K/V frags
// shared across sub-tiles -> LDS traffic halved per output. Base-2 softmax.
// Partials: o_part bf16 [n*NQB+qbi][S][128 i][128 c], m/l f32.
// ---------------------------------------------------------------------------
__global__ __launch_bounds__(256, 3) void attn_kernel(
    const unsigned short* __restrict__ qkv,
    unsigned short* __restrict__ o_part,
    float* __restrict__ m_part,
    float* __restrict__ l_part,
    int S, int TILES_PER)
{
    __shared__ alignas(16) unsigned char kv_lds[2][24*1024];

    const unsigned short* q_t = qkv;
    const unsigned short* k_t = qkv + (size_t)N_ * L_ * CR_;
    const unsigned short* v   = qkv + (size_t)2 * N_ * L_ * CR_;

    const int blk  = blockIdx.x;
    const int n    = blk / (NQB * S);
    const int rem  = blk % (NQB * S);
    const int qbi  = rem / S;
    const int s    = rem % S;
    const int qb   = qbi * QBLK;
    const int tid  = threadIdx.x;
    const int wave = tid >> 6;
    const int lane = tid & 63;
    const int lhi  = lane >> 4;    // 0..3
    const int llo  = lane & 15;    // q-row i within sub-tile

    const int jb_beg = s * TILES_PER * KVBLK;
    const int jb_end = min(L_, jb_beg + TILES_PER * KVBLK);

    const unsigned short* qtb = q_t + (size_t)n * L_ * CR_;
    const unsigned short* ktb = k_t + (size_t)n * L_ * CR_;
    const unsigned short* vb  = v   + (size_t)n * C_ * L_;

    // Q B-fragments for both sub-tiles
    bf16x8 qf[2][2];
    #pragma unroll
    for (int st = 0; st < 2; st++) {
        int row = qb + wave * 32 + st * 16 + llo;
        #pragma unroll
        for (int ks = 0; ks < 2; ks++)
            qf[st][ks] = *reinterpret_cast<const bf16x8*>(qtb + (size_t)row * CR_ + ks*32 + lhi*8);
    }

    // staging source addresses (pre-swizzled global, linear LDS dest)
    const int l8 = lane >> 3;          // 0..7
    const int l7 = (lane & 7) * 16;    // byte chunk within 128B row
    const int rho0 = wave*16 + l8;
    const int rho1 = rho0 + 8;
    const unsigned short* kbase0 = ktb + (size_t)sigma_(rho0) * CR_ + ((l7 ^ ((rho0 & 7) << 4)) >> 1);
    const unsigned short* kbase1 = ktb + (size_t)sigma_(rho1) * CR_ + ((l7 ^ ((rho1 & 7) << 4)) >> 1);
    const unsigned short* vbase[4];
    #pragma unroll
    for (int vt = 0; vt < 4; vt++) {
        int c = wave*32 + vt*8 + l8;
        vbase[vt] = vb + (size_t)c * L_ + ((l7 ^ (l8 << 4)) >> 1);
    }

    #define STAGE(b, jb_) do {                                                   \
        GLD16(kbase0 + (size_t)(jb_) * CR_, &kv_lds[b][(wave*2+0)*1024 + 0]);    \
        GLD16(kbase1 + (size_t)(jb_) * CR_, &kv_lds[b][(wave*2+1)*1024 + 0]);    \
        GLD16(vbase[0] + (jb_), &kv_lds[b][8192 + (wave*4+0)*1024]);             \
        GLD16(vbase[1] + (jb_), &kv_lds[b][8192 + (wave*4+1)*1024]);             \
        GLD16(vbase[2] + (jb_), &kv_lds[b][8192 + (wave*4+2)*1024]);             \
        GLD16(vbase[3] + (jb_), &kv_lds[b][8192 + (wave*4+3)*1024]);             \
    } while (0)

    f32x4 o_acc[2][8];
    #pragma unroll
    for (int st = 0; st < 2; st++)
        #pragma unroll
        for (int ct = 0; ct < 8; ct++) o_acc[st][ct] = f32x4{0.f, 0.f, 0.f, 0.f};
    float m_run[2] = {-INFINITY, -INFINITY};
    float l_run[2] = {0.f, 0.f};

    int cur = 0;
    STAGE(0, jb_beg);
    __syncthreads();

    for (int jb = jb_beg; jb < jb_end; jb += KVBLK) {
        if (jb + KVBLK < jb_end) STAGE(cur ^ 1, jb + KVBLK);

        const unsigned char* kbuf = &kv_lds[cur][0];
        const unsigned char* vbuf = &kv_lds[cur][8192];

        // ---- S^T = K . Q^T, both sub-tiles share kf ----
        f32x4 sacc[2][4];
        #pragma unroll
        for (int st = 0; st < 2; st++)
            #pragma unroll
            for (int jt = 0; jt < 4; jt++) sacc[st][jt] = f32x4{0.f, 0.f, 0.f, 0.f};
        #pragma unroll
        for (int ks = 0; ks < 2; ks++) {
            #pragma unroll
            for (int jt = 0; jt < 4; jt++) {
                int rho  = jt*16 + llo;
                int colb = ks*64 + lhi*16;
                bf16x8 kf = *reinterpret_cast<const bf16x8*>(
                    kbuf + rho*128 + (colb ^ ((rho & 7) << 4)));
                sacc[0][jt] = __builtin_amdgcn_mfma_f32_16x16x32_bf16(kf, qf[0][ks], sacc[0][jt], 0, 0, 0);
                sacc[1][jt] = __builtin_amdgcn_mfma_f32_16x16x32_bf16(kf, qf[1][ks], sacc[1][jt], 0, 0, 0);
            }
        }

        // ---- online softmax, base-2 domain ----
        float tm[2];
        #pragma unroll
        for (int st = 0; st < 2; st++) {
            float m = sacc[st][0][0];
            #pragma unroll
            for (int jt = 0; jt < 4; jt++)
                #pragma unroll
                for (int r = 0; r < 4; r++) m = fmaxf(m, sacc[st][jt][r]);
            m = fmaxf(m, __shfl_xor(m, 16, 64));
            m = fmaxf(m, __shfl_xor(m, 32, 64));
            tm[st] = m;
        }
        if (!__all(tm[0] <= m_run[0] + 11.f && tm[1] <= m_run[1] + 11.f)) {
            #pragma unroll
            for (int st = 0; st < 2; st++) {
                float mn = fmaxf(m_run[st], tm[st]);
                float sc = exp2_fast(m_run[st] - mn);
                #pragma unroll
                for (int ct = 0; ct < 8; ct++)
                    #pragma unroll
                    for (int r = 0; r < 4; r++) o_acc[st][ct][r] *= sc;
                l_run[st] *= sc;
                m_run[st] = mn;
            }
        }
        unsigned pk[2][8];
        #pragma unroll
        for (int st = 0; st < 2; st++) {
            float rs = 0.f;
            #pragma unroll
            for (int jt = 0; jt < 4; jt++) {
                float pa = exp2_fast(sacc[st][jt][0] - m_run[st]);
                float pb = exp2_fast(sacc[st][jt][1] - m_run[st]);
                float pc = exp2_fast(sacc[st][jt][2] - m_run[st]);
                float pd = exp2_fast(sacc[st][jt][3] - m_run[st]);
                rs += (pa + pb) + (pc + pd);
                pk[st][jt*2 + 0] = cvt_pk_bf16(pa, pb);
                pk[st][jt*2 + 1] = cvt_pk_bf16(pc, pd);
            }
            rs += __shfl_xor(rs, 16, 64);
            rs += __shfl_xor(rs, 32, 64);
            l_run[st] += rs;
        }

        // ---- O^T += V^T . P^T, both sub-tiles share vf ----
        #pragma unroll
        for (int ks = 0; ks < 2; ks++) {
            bf16x8 pf0 = *reinterpret_cast<const bf16x8*>(&pk[0][4*ks]);
            bf16x8 pf1 = *reinterpret_cast<const bf16x8*>(&pk[1][4*ks]);
            #pragma unroll
            for (int ct = 0; ct < 8; ct++) {
                int c = ct*16 + llo;
                int colb = ks*64 + lhi*16;
                bf16x8 vf = *reinterpret_cast<const bf16x8*>(
                    vbuf + c*128 + (colb ^ ((c & 7) << 4)));
                o_acc[0][ct] = __builtin_amdgcn_mfma_f32_16x16x32_bf16(vf, pf0, o_acc[0][ct], 0, 0, 0);
                o_acc[1][ct] = __builtin_amdgcn_mfma_f32_16x16x32_bf16(vf, pf1, o_acc[1][ct], 0, 0, 0);
            }
        }

        __syncthreads();
        cur ^= 1;
    }

    // ---- write partials: o_acc[st][ct][r] = O[c=ct*16+lhi*4+r][i=wave*32+st*16+llo] ----
    unsigned short* ob = o_part + ((size_t)(n*NQB + qbi)*S + s) * (QBLK*C_);
    float* mb = m_part + ((size_t)(n*NQB + qbi)*S + s) * QBLK;
    float* lb = l_part + ((size_t)(n*NQB + qbi)*S + s) * QBLK;
    #pragma unroll
    for (int st = 0; st < 2; st++) {
        int i_loc = wave*32 + st*16 + llo;
        #pragma unroll
        for (int ct = 0; ct < 8; ct++) {
            int c0 = ct*16 + lhi*4;
            uint2 pkd;
            pkd.x = cvt_pk_bf16(o_acc[st][ct][0], o_acc[st][ct][1]);
            pkd.y = cvt_pk_bf16(o_acc[st][ct][2], o_acc[st][ct][3]);
            *reinterpret_cast<uint2*>(ob + (size_t)i_loc * C_ + c0) = pkd;
        }
        if (lhi == 0) {
            mb[i_loc] = m_run[st];
            lb[i_loc] = l_run[st];
        }
    }
    #undef STAGE
}

// ---------------------------------------------------------------------------
// Combine: out[n][c][i] = (sum_s O_s[i][c] * 2^(m_s-M)) / (sum_s l_s*2^(m_s-M)) + x
// Block = (n, q-tile, i-chunk of 32). 256 threads: (i=tid>>3, c-group=tid&7).
// ---------------------------------------------------------------------------
__global__ __launch_bounds__(256) void combine_kernel(
    const unsigned short* __restrict__ o_part,
    const float* __restrict__ m_part,
    const float* __restrict__ l_part,
    const float* __restrict__ x,
    float* __restrict__ out,
    int S)
{
    __shared__ float wls[SMAX][32];
    __shared__ float invl[32];

    const int blk  = blockIdx.x;
    const int part = blk & 3;
    const int qbi  = (blk >> 2) % NQB;
    const int n    = blk / (4 * NQB);
    const int tid  = threadIdx.x;
    const int i0   = part * 32;

    const size_t pbase = (size_t)(n*NQB + qbi) * S;

    if (tid < 32) {
        float m[SMAX], l[SMAX];
        float M = -INFINITY;
        for (int s = 0; s < S; s++) {
            m[s] = m_part[(pbase + s) * QBLK + i0 + tid];
            l[s] = l_part[(pbase + s) * QBLK + i0 + tid];
            M = fmaxf(M, m[s]);
        }
        float lt = 0.f;
        for (int s = 0; s < S; s++) {
            float w = exp2_fast(m[s] - M);
            wls[s][tid] = w;
            lt += w * l[s];
        }
        invl[tid] = 1.0f / lt;
    }
    __syncthreads();

    const int il = tid >> 3;           // 0..31
    const int cg = tid & 7;            // c-group: c = cg*16 .. +15

    float acc[16];
    #pragma unroll
    for (int k = 0; k < 16; k++) acc[k] = 0.f;

    for (int s = 0; s < S; s++) {
        const unsigned short* src = o_part + (pbase + s) * (QBLK*C_) + (size_t)(i0 + il) * C_ + cg*16;
        bf16x8 v0 = *reinterpret_cast<const bf16x8*>(src);
        bf16x8 v1 = *reinterpret_cast<const bf16x8*>(src + 8);
        float w = wls[s][il];
        #pragma unroll
        for (int k = 0; k < 8; k++) acc[k]     += w * bf2f((unsigned short)v0[k]);
        #pragma unroll
        for (int k = 0; k < 8; k++) acc[8 + k] += w * bf2f((unsigned short)v1[k]);
    }

    const float nv = invl[il];
    const int ig = qbi*QBLK + i0 + il;
    const float* xb = x   + (size_t)n * C_ * L_;
    float*       ob = out + (size_t)n * C_ * L_;
    #pragma unroll
    for (int k = 0; k < 16; k++) {
        int c = cg*16 + k;
        ob[(size_t)c * L_ + ig] = acc[k] * nv + xb[(size_t)c * L_ + ig];
    }
}

extern "C" void kernel_launch(void* const* d_in, const int* in_sizes, int n_in,
                              void* d_out, int out_size, void* d_ws, size_t ws_size,
                              hipStream_t stream) {
    const float* x  = (const float*)d_in[0];
    const float* w1 = (const float*)d_in[1];
    const float* b1 = (const float*)d_in[2];
    const float* a1 = (const float*)d_in[3];
    const float* w2 = (const float*)d_in[4];
    const float* b2 = (const float*)d_in[5];
    const float* a2 = (const float*)d_in[6];
    const float* wa = (const float*)d_in[7];
    const float* ba = (const float*)d_in[8];
    const float* aa = (const float*)d_in[9];
    float* out = (float*)d_out;

    unsigned short* qkv = (unsigned short*)d_ws;
    size_t qkv_bytes = ((size_t)2*N_*L_*CR_ + (size_t)N_*C_*L_) * 2;
    size_t off = (qkv_bytes + 255) & ~(size_t)255;

    // largest S<=8 fitting in ws (deterministic: ws_size fixed)
    int S = SMAX;
    while (S > 1) {
        size_t need = off + (size_t)N_*NQB*S * ((size_t)QBLK*C_*2 + 2*QBLK*4);
        if (need <= ws_size) break;
        S--;
    }
    unsigned short* o_part = (unsigned short*)((char*)d_ws + off);
    size_t o_elems = (size_t)N_*NQB*S*QBLK*C_;
    float* m_part = (float*)(o_part + o_elems);
    float* l_part = m_part + (size_t)N_*NQB*S*QBLK;
    int tiles_per = (L_/KVBLK + S - 1) / S;

    proj_kernel<<<N_ * (L_/32), 256, 0, stream>>>(x, w1, b1, a1, w2, b2, a2, wa, ba, aa, qkv);
    attn_kernel<<<N_ * NQB * S, 256, 0, stream>>>(qkv, o_part, m_part, l_part, S, tiles_per);
    combine_kernel<<<N_ * NQB * 4, 256, 0, stream>>>(o_part, m_part, l_part, x, out, S);
}